// Round 2
// baseline (1974.930 us; speedup 1.0000x reference)
//
#include <hip/hip_runtime.h>
#include <stdint.h>

#define N_NODES 100000
#define N_EDGES 1600000
#define HDIM    128
#define G_GRAPHS 64
#define NTOT (N_EDGES + N_NODES)
#define SCAN_NB ((N_NODES + 2047) / 2048)   // 49

static_assert(N_NODES % 16 == 0, "tile");
static_assert(SCAN_NB <= 64, "scan2 single wave");

// ---- degree (weighted) + in-edge count histogram ----
__global__ void k_deg_cnt(const int* __restrict__ ei, const float* __restrict__ ew,
                          float* __restrict__ deg, int* __restrict__ cnt) {
    int e = blockIdx.x * 256 + threadIdx.x;
    if (e >= N_EDGES) return;
    int dst = ei[N_EDGES + e];
    atomicAdd(&deg[dst], ew[e]);
    atomicAdd(&cnt[dst], 1);
}

// ---- dinv = rsqrt(deg + 1)  (self-loop weight 1 -> deg always > 0) ----
__global__ void k_dinv(const float* __restrict__ deg, float* __restrict__ dinv) {
    int i = blockIdx.x * 256 + threadIdx.x;
    if (i >= N_NODES) return;
    dinv[i] = 1.0f / sqrtf(deg[i] + 1.0f);
}

// ---- exclusive scan of (cnt[i]+1), 3 phases ----
__global__ void k_scan1(const int* __restrict__ cnt, int* __restrict__ partial) {
    int tid = threadIdx.x;
    int base = blockIdx.x * 2048 + tid * 8;
    int s = 0;
#pragma unroll
    for (int j = 0; j < 8; j++) {
        int i = base + j;
        if (i < N_NODES) s += cnt[i] + 1;
    }
    for (int off = 32; off; off >>= 1) s += __shfl_down(s, off);
    __shared__ int sw[4];
    if ((tid & 63) == 0) sw[tid >> 6] = s;
    __syncthreads();
    if (tid == 0) partial[blockIdx.x] = sw[0] + sw[1] + sw[2] + sw[3];
}

__global__ void k_scan2(int* __restrict__ partial) {
    int lane = threadIdx.x;
    int v = (lane < SCAN_NB) ? partial[lane] : 0;
    int orig = v;
    for (int off = 1; off < 64; off <<= 1) {
        int u = __shfl_up(v, off);
        if (lane >= off) v += u;
    }
    if (lane < SCAN_NB) partial[lane] = v - orig;   // exclusive
}

__global__ void k_scan3(const int* __restrict__ cnt, const int* __restrict__ partial,
                        int* __restrict__ offs) {
    int tid = threadIdx.x;
    int base = blockIdx.x * 2048 + tid * 8;
    int vals[8];
    int tsum = 0;
#pragma unroll
    for (int j = 0; j < 8; j++) {
        int i = base + j;
        vals[j] = (i < N_NODES) ? cnt[i] + 1 : 0;
        tsum += vals[j];
    }
    __shared__ int s[256];
    s[tid] = tsum;
    __syncthreads();
    for (int off = 1; off < 256; off <<= 1) {
        int v = 0;
        if (tid >= off) v = s[tid - off];
        __syncthreads();
        s[tid] += v;
        __syncthreads();
    }
    int run = partial[blockIdx.x] + s[tid] - tsum;   // block base + thread-exclusive
#pragma unroll
    for (int j = 0; j < 8; j++) {
        int i = base + j;
        if (i < N_NODES) offs[i] = run;
        run += vals[j];
    }
}

// ---- fill CSR (grouped by dst), includes self loops; entry = (src, norm) ----
__global__ void k_fill(const int* __restrict__ ei, const float* __restrict__ ew,
                       const float* __restrict__ dinv, const int* __restrict__ offs,
                       int* __restrict__ fill, int2* __restrict__ csr) {
    int e = blockIdx.x * 256 + threadIdx.x;
    if (e < N_EDGES) {
        int src = ei[e];
        int dst = ei[N_EDGES + e];
        float nrm = dinv[src] * ew[e] * dinv[dst];
        int p = offs[dst] + atomicAdd(&fill[dst], 1);
        csr[p] = make_int2(src, __float_as_int(nrm));
    } else if (e < NTOT) {
        int i = e - N_EDGES;
        float d = dinv[i];
        int p = offs[i] + atomicAdd(&fill[i], 1);
        csr[p] = make_int2(i, __float_as_int(d * d));
    }
}

// ---- dense transform t = h @ W (W f32 staged in LDS) ----
__global__ __launch_bounds__(256) void k_transform(const float* __restrict__ hin,
                                                   const float* __restrict__ Wg,
                                                   float* __restrict__ t) {
    __shared__ float Wl[HDIM * HDIM];     // 64 KB
    __shared__ float hl[16 * 129];        // padded rows
    int tid = threadIdx.x;
    const float4* W4 = (const float4*)Wg;  // 4096 float4
#pragma unroll
    for (int i = tid; i < 4096; i += 256) {
        float4 v = W4[i];
        int b = i * 4;
        Wl[b + 0] = v.x; Wl[b + 1] = v.y; Wl[b + 2] = v.z; Wl[b + 3] = v.w;
    }
    __syncthreads();
    int ty = tid >> 4, tx = tid & 15;
    for (int tile = blockIdx.x; tile < N_NODES / 16; tile += gridDim.x) {
        int r = tile * 16 + ty;
        float* hp = &hl[ty * 129 + tx * 8];
        const float4* h4 = (const float4*)&hin[(size_t)r * HDIM + tx * 8];
        float4 a = h4[0], b = h4[1];
        hp[0] = a.x; hp[1] = a.y; hp[2] = a.z; hp[3] = a.w;
        hp[4] = b.x; hp[5] = b.y; hp[6] = b.z; hp[7] = b.w;
        __syncthreads();
        float acc[8];
#pragma unroll
        for (int j = 0; j < 8; j++) acc[j] = 0.f;
        const float* hrow = &hl[ty * 129];
#pragma unroll 4
        for (int k = 0; k < HDIM; k++) {
            float av = hrow[k];
            const float4* wr = (const float4*)&Wl[k * HDIM + tx * 8];
            float4 b0 = wr[0], b1 = wr[1];
            acc[0] += av * b0.x; acc[1] += av * b0.y; acc[2] += av * b0.z; acc[3] += av * b0.w;
            acc[4] += av * b1.x; acc[5] += av * b1.y; acc[6] += av * b1.z; acc[7] += av * b1.w;
        }
        float4* t4 = (float4*)&t[(size_t)r * HDIM + tx * 8];
        t4[0] = make_float4(acc[0], acc[1], acc[2], acc[3]);
        t4[1] = make_float4(acc[4], acc[5], acc[6], acc[7]);
        __syncthreads();
    }
}

// ---- aggregation: one wave per node, lane holds float2 of H; + bias + relu ----
__global__ void k_aggregate(const float* __restrict__ t, const int* __restrict__ offs,
                            const int* __restrict__ cnt, const int2* __restrict__ csr,
                            const float* __restrict__ bias, float* __restrict__ hout) {
    int tid = threadIdx.x;
    int node = blockIdx.x * 4 + (tid >> 6);
    int lane = tid & 63;
    if (node >= N_NODES) return;
    int beg = offs[node];
    int num = cnt[node] + 1;
    const float2* t2 = (const float2*)t;
    float ax = 0.f, ay = 0.f;
    for (int j = 0; j < num; j++) {
        int2 sw = csr[beg + j];
        float w = __int_as_float(sw.y);
        float2 v = t2[(size_t)sw.x * 64 + lane];
        ax += w * v.x;
        ay += w * v.y;
    }
    float2 bb = ((const float2*)bias)[lane];
    ax = fmaxf(ax + bb.x, 0.f);
    ay = fmaxf(ay + bb.y, 0.f);
    ((float2*)hout)[(size_t)node * 64 + lane] = make_float2(ax, ay);
}

// ---- mean pool (atomic partials) ----
__global__ void k_pool(const float* __restrict__ h, const int* __restrict__ batch,
                       float* __restrict__ pooled, int* __restrict__ gcnt) {
    int tid = threadIdx.x;
    int node = blockIdx.x * 4 + (tid >> 6);
    int lane = tid & 63;
    if (node >= N_NODES) return;
    int g = batch[node];
    float2 v = ((const float2*)h)[(size_t)node * 64 + lane];
    atomicAdd(&pooled[g * HDIM + 2 * lane], v.x);
    atomicAdd(&pooled[g * HDIM + 2 * lane + 1], v.y);
    if (lane == 0) atomicAdd(&gcnt[g], 1);
}

// ---- final linear: out[g] = (pooled_sum . lin_w)/cnt + lin_b ----
__global__ void k_final(const float* __restrict__ pooled, const int* __restrict__ gcnt,
                        const float* __restrict__ lw, const float* __restrict__ lb,
                        float* __restrict__ out) {
    int g = blockIdx.x;
    int lane = threadIdx.x;
    float2 p = ((const float2*)pooled)[g * 64 + lane];
    float2 wv = ((const float2*)lw)[lane];
    float d = p.x * wv.x + p.y * wv.y;
    for (int off = 32; off; off >>= 1) d += __shfl_down(d, off);
    if (lane == 0) {
        float c = fmaxf((float)gcnt[g], 1.0f);
        out[g] = d / c + lb[0];
    }
}

extern "C" void kernel_launch(void* const* d_in, const int* in_sizes, int n_in,
                              void* d_out, int out_size, void* d_ws, size_t ws_size,
                              hipStream_t stream) {
    const float* x   = (const float*)d_in[0];
    const float* ew  = (const float*)d_in[1];
    const int*   ei  = (const int*)d_in[2];
    const int*   bat = (const int*)d_in[3];
    const float* W1  = (const float*)d_in[4];
    const float* b1  = (const float*)d_in[5];
    const float* W2  = (const float*)d_in[6];
    const float* b2  = (const float*)d_in[7];
    const float* W3  = (const float*)d_in[8];
    const float* b3  = (const float*)d_in[9];
    const float* lw  = (const float*)d_in[10];
    const float* lb  = (const float*)d_in[11];
    float* out = (float*)d_out;

    char* w = (char*)d_ws;
    size_t o = 0;
    auto carve = [&](size_t bytes) -> void* {
        void* p = w + o;
        o = (o + bytes + 255) & ~(size_t)255;
        return p;
    };
    float* deg   = (float*)carve((size_t)N_NODES * 4);
    int*   cnt   = (int*)  carve((size_t)N_NODES * 4);
    int*   fill  = (int*)  carve((size_t)N_NODES * 4);
    char*  zero1_end = w + o;                     // deg..fill span
    float* dinv  = (float*)carve((size_t)N_NODES * 4);
    int*   offs  = (int*)  carve((size_t)N_NODES * 4);
    int*   part  = (int*)  carve(64 * 4);
    int2*  csr   = (int2*) carve((size_t)NTOT * 8);
    float* t     = (float*)carve((size_t)N_NODES * HDIM * 4);
    float* h     = (float*)carve((size_t)N_NODES * HDIM * 4);
    char*  zero2_beg = w + o;
    float* pooled = (float*)carve((size_t)G_GRAPHS * HDIM * 4);
    int*   gcnt   = (int*)  carve((size_t)G_GRAPHS * 4);
    char*  zero2_end = w + o;
    (void)ws_size; (void)in_sizes; (void)n_in; (void)out_size;

    hipMemsetAsync(deg, 0, (size_t)(zero1_end - (char*)deg), stream);
    hipMemsetAsync(zero2_beg, 0, (size_t)(zero2_end - zero2_beg), stream);

    k_deg_cnt<<<(N_EDGES + 255) / 256, 256, 0, stream>>>(ei, ew, deg, cnt);
    k_dinv<<<(N_NODES + 255) / 256, 256, 0, stream>>>(deg, dinv);
    k_scan1<<<SCAN_NB, 256, 0, stream>>>(cnt, part);
    k_scan2<<<1, 64, 0, stream>>>(part);
    k_scan3<<<SCAN_NB, 256, 0, stream>>>(cnt, part, offs);
    k_fill<<<(NTOT + 255) / 256, 256, 0, stream>>>(ei, ew, dinv, offs, fill, csr);

    k_transform<<<512, 256, 0, stream>>>(x, W1, t);
    k_aggregate<<<N_NODES / 4, 256, 0, stream>>>(t, offs, cnt, csr, b1, h);
    k_transform<<<512, 256, 0, stream>>>(h, W2, t);
    k_aggregate<<<N_NODES / 4, 256, 0, stream>>>(t, offs, cnt, csr, b2, h);
    k_transform<<<512, 256, 0, stream>>>(h, W3, t);
    k_aggregate<<<N_NODES / 4, 256, 0, stream>>>(t, offs, cnt, csr, b3, h);

    k_pool<<<N_NODES / 4, 256, 0, stream>>>(h, bat, pooled, gcnt);
    k_final<<<G_GRAPHS, 64, 0, stream>>>(pooled, gcnt, lw, lb, out);
}

// Round 3
// 1424.675 us; speedup vs baseline: 1.3862x; 1.3862x over previous
//
#include <hip/hip_runtime.h>
#include <stdint.h>

#define N_NODES 100000
#define N_EDGES 1600000
#define HDIM    128
#define G_GRAPHS 64
#define NTOT (N_EDGES + N_NODES)
#define SCAN_NB ((N_NODES + 2047) / 2048)   // 49

static_assert(N_NODES % 16 == 0, "tile");
static_assert(SCAN_NB <= 64, "scan2 single wave");

// ---- degree (weighted) + in-edge count histogram ----
__global__ void k_deg_cnt(const int* __restrict__ ei, const float* __restrict__ ew,
                          float* __restrict__ deg, int* __restrict__ cnt) {
    int e = blockIdx.x * 256 + threadIdx.x;
    if (e >= N_EDGES) return;
    int dst = ei[N_EDGES + e];
    atomicAdd(&deg[dst], ew[e]);
    atomicAdd(&cnt[dst], 1);
}

// ---- dinv = rsqrt(deg + 1)  (self-loop weight 1 -> deg always > 0) ----
__global__ void k_dinv(const float* __restrict__ deg, float* __restrict__ dinv) {
    int i = blockIdx.x * 256 + threadIdx.x;
    if (i >= N_NODES) return;
    dinv[i] = 1.0f / sqrtf(deg[i] + 1.0f);
}

// ---- exclusive scan of (cnt[i]+1), 3 phases ----
__global__ void k_scan1(const int* __restrict__ cnt, int* __restrict__ partial) {
    int tid = threadIdx.x;
    int base = blockIdx.x * 2048 + tid * 8;
    int s = 0;
#pragma unroll
    for (int j = 0; j < 8; j++) {
        int i = base + j;
        if (i < N_NODES) s += cnt[i] + 1;
    }
    for (int off = 32; off; off >>= 1) s += __shfl_down(s, off);
    __shared__ int sw[4];
    if ((tid & 63) == 0) sw[tid >> 6] = s;
    __syncthreads();
    if (tid == 0) partial[blockIdx.x] = sw[0] + sw[1] + sw[2] + sw[3];
}

__global__ void k_scan2(int* __restrict__ partial) {
    int lane = threadIdx.x;
    int v = (lane < SCAN_NB) ? partial[lane] : 0;
    int orig = v;
    for (int off = 1; off < 64; off <<= 1) {
        int u = __shfl_up(v, off);
        if (lane >= off) v += u;
    }
    if (lane < SCAN_NB) partial[lane] = v - orig;   // exclusive
}

__global__ void k_scan3(const int* __restrict__ cnt, const int* __restrict__ partial,
                        int* __restrict__ offs) {
    int tid = threadIdx.x;
    int base = blockIdx.x * 2048 + tid * 8;
    int vals[8];
    int tsum = 0;
#pragma unroll
    for (int j = 0; j < 8; j++) {
        int i = base + j;
        vals[j] = (i < N_NODES) ? cnt[i] + 1 : 0;
        tsum += vals[j];
    }
    __shared__ int s[256];
    s[tid] = tsum;
    __syncthreads();
    for (int off = 1; off < 256; off <<= 1) {
        int v = 0;
        if (tid >= off) v = s[tid - off];
        __syncthreads();
        s[tid] += v;
        __syncthreads();
    }
    int run = partial[blockIdx.x] + s[tid] - tsum;   // block base + thread-exclusive
#pragma unroll
    for (int j = 0; j < 8; j++) {
        int i = base + j;
        if (i < N_NODES) offs[i] = run;
        run += vals[j];
    }
}

// ---- fill CSR (grouped by dst), includes self loops; entry = (src, norm) ----
__global__ void k_fill(const int* __restrict__ ei, const float* __restrict__ ew,
                       const float* __restrict__ dinv, const int* __restrict__ offs,
                       int* __restrict__ fill, int2* __restrict__ csr) {
    int e = blockIdx.x * 256 + threadIdx.x;
    if (e < N_EDGES) {
        int src = ei[e];
        int dst = ei[N_EDGES + e];
        float nrm = dinv[src] * ew[e] * dinv[dst];
        int p = offs[dst] + atomicAdd(&fill[dst], 1);
        csr[p] = make_int2(src, __float_as_int(nrm));
    } else if (e < NTOT) {
        int i = e - N_EDGES;
        float d = dinv[i];
        int p = offs[i] + atomicAdd(&fill[i], 1);
        csr[p] = make_int2(i, __float_as_int(d * d));
    }
}

// ---- dense transform t = h @ W (W f32 staged in LDS) ----
__global__ __launch_bounds__(256) void k_transform(const float* __restrict__ hin,
                                                   const float* __restrict__ Wg,
                                                   float* __restrict__ t) {
    __shared__ float Wl[HDIM * HDIM];     // 64 KB
    __shared__ float hl[16 * 129];        // padded rows
    int tid = threadIdx.x;
    const float4* W4 = (const float4*)Wg;  // 4096 float4
#pragma unroll
    for (int i = tid; i < 4096; i += 256) {
        float4 v = W4[i];
        int b = i * 4;
        Wl[b + 0] = v.x; Wl[b + 1] = v.y; Wl[b + 2] = v.z; Wl[b + 3] = v.w;
    }
    __syncthreads();
    int ty = tid >> 4, tx = tid & 15;
    for (int tile = blockIdx.x; tile < N_NODES / 16; tile += gridDim.x) {
        int r = tile * 16 + ty;
        float* hp = &hl[ty * 129 + tx * 8];
        const float4* h4 = (const float4*)&hin[(size_t)r * HDIM + tx * 8];
        float4 a = h4[0], b = h4[1];
        hp[0] = a.x; hp[1] = a.y; hp[2] = a.z; hp[3] = a.w;
        hp[4] = b.x; hp[5] = b.y; hp[6] = b.z; hp[7] = b.w;
        __syncthreads();
        float acc[8];
#pragma unroll
        for (int j = 0; j < 8; j++) acc[j] = 0.f;
        const float* hrow = &hl[ty * 129];
#pragma unroll 4
        for (int k = 0; k < HDIM; k++) {
            float av = hrow[k];
            const float4* wr = (const float4*)&Wl[k * HDIM + tx * 8];
            float4 b0 = wr[0], b1 = wr[1];
            acc[0] += av * b0.x; acc[1] += av * b0.y; acc[2] += av * b0.z; acc[3] += av * b0.w;
            acc[4] += av * b1.x; acc[5] += av * b1.y; acc[6] += av * b1.z; acc[7] += av * b1.w;
        }
        float4* t4 = (float4*)&t[(size_t)r * HDIM + tx * 8];
        t4[0] = make_float4(acc[0], acc[1], acc[2], acc[3]);
        t4[1] = make_float4(acc[4], acc[5], acc[6], acc[7]);
        __syncthreads();
    }
}

// ---- aggregation: one wave per node, lane holds float2 of H; + bias + relu ----
__global__ void k_aggregate(const float* __restrict__ t, const int* __restrict__ offs,
                            const int* __restrict__ cnt, const int2* __restrict__ csr,
                            const float* __restrict__ bias, float* __restrict__ hout) {
    int tid = threadIdx.x;
    int node = blockIdx.x * 4 + (tid >> 6);
    int lane = tid & 63;
    if (node >= N_NODES) return;
    int beg = offs[node];
    int num = cnt[node] + 1;
    const float2* t2 = (const float2*)t;
    float ax = 0.f, ay = 0.f;
    for (int j = 0; j < num; j++) {
        int2 sw = csr[beg + j];
        float w = __int_as_float(sw.y);
        float2 v = t2[(size_t)sw.x * 64 + lane];
        ax += w * v.x;
        ay += w * v.y;
    }
    float2 bb = ((const float2*)bias)[lane];
    ax = fmaxf(ax + bb.x, 0.f);
    ay = fmaxf(ay + bb.y, 0.f);
    ((float2*)hout)[(size_t)node * 64 + lane] = make_float2(ax, ay);
}

// ---- fused mean-pool + final linear: one block per graph (batch is sorted) ----
__global__ __launch_bounds__(256) void k_pool_final(const float* __restrict__ h,
                                                    const int* __restrict__ batch,
                                                    const float* __restrict__ lw,
                                                    const float* __restrict__ lb,
                                                    float* __restrict__ out) {
    int g = blockIdx.x;
    int tid = threadIdx.x;
    // wave-uniform binary searches: beg = lower_bound(g), end = lower_bound(g+1)
    int lo = 0, hi = N_NODES;
    while (lo < hi) { int m = (lo + hi) >> 1; if (batch[m] < g) lo = m + 1; else hi = m; }
    int beg = lo;
    hi = N_NODES;
    while (lo < hi) { int m = (lo + hi) >> 1; if (batch[m] < g + 1) lo = m + 1; else hi = m; }
    int end = lo;

    int col = tid & 127;
    int half = tid >> 7;           // 0 or 1
    float s = 0.f;
    for (int n = beg + half; n < end; n += 2)
        s += h[(size_t)n * HDIM + col];

    __shared__ float sm[256];
    sm[tid] = s;
    __syncthreads();
    float dp = 0.f;
    if (tid < HDIM) dp = (sm[tid] + sm[tid + HDIM]) * lw[tid];
    __syncthreads();
    sm[tid] = dp;
    __syncthreads();
    if (tid < 64) {
        float v = sm[tid] + sm[tid + 64];
        for (int off = 32; off; off >>= 1) v += __shfl_down(v, off);
        if (tid == 0) {
            float c = fmaxf((float)(end - beg), 1.0f);
            out[g] = v / c + lb[0];
        }
    }
}

extern "C" void kernel_launch(void* const* d_in, const int* in_sizes, int n_in,
                              void* d_out, int out_size, void* d_ws, size_t ws_size,
                              hipStream_t stream) {
    const float* x   = (const float*)d_in[0];
    const float* ew  = (const float*)d_in[1];
    const int*   ei  = (const int*)d_in[2];
    const int*   bat = (const int*)d_in[3];
    const float* W1  = (const float*)d_in[4];
    const float* b1  = (const float*)d_in[5];
    const float* W2  = (const float*)d_in[6];
    const float* b2  = (const float*)d_in[7];
    const float* W3  = (const float*)d_in[8];
    const float* b3  = (const float*)d_in[9];
    const float* lw  = (const float*)d_in[10];
    const float* lb  = (const float*)d_in[11];
    float* out = (float*)d_out;

    char* w = (char*)d_ws;
    size_t o = 0;
    auto carve = [&](size_t bytes) -> void* {
        void* p = w + o;
        o = (o + bytes + 255) & ~(size_t)255;
        return p;
    };
    float* deg   = (float*)carve((size_t)N_NODES * 4);
    int*   cnt   = (int*)  carve((size_t)N_NODES * 4);
    int*   fill  = (int*)  carve((size_t)N_NODES * 4);
    char*  zero1_end = w + o;                     // deg..fill span
    float* dinv  = (float*)carve((size_t)N_NODES * 4);
    int*   offs  = (int*)  carve((size_t)N_NODES * 4);
    int*   part  = (int*)  carve(64 * 4);
    int2*  csr   = (int2*) carve((size_t)NTOT * 8);
    float* t     = (float*)carve((size_t)N_NODES * HDIM * 4);
    float* h     = (float*)carve((size_t)N_NODES * HDIM * 4);
    (void)ws_size; (void)in_sizes; (void)n_in; (void)out_size;

    hipMemsetAsync(deg, 0, (size_t)(zero1_end - (char*)deg), stream);

    k_deg_cnt<<<(N_EDGES + 255) / 256, 256, 0, stream>>>(ei, ew, deg, cnt);
    k_dinv<<<(N_NODES + 255) / 256, 256, 0, stream>>>(deg, dinv);
    k_scan1<<<SCAN_NB, 256, 0, stream>>>(cnt, part);
    k_scan2<<<1, 64, 0, stream>>>(part);
    k_scan3<<<SCAN_NB, 256, 0, stream>>>(cnt, part, offs);
    k_fill<<<(NTOT + 255) / 256, 256, 0, stream>>>(ei, ew, dinv, offs, fill, csr);

    k_transform<<<512, 256, 0, stream>>>(x, W1, t);
    k_aggregate<<<N_NODES / 4, 256, 0, stream>>>(t, offs, cnt, csr, b1, h);
    k_transform<<<512, 256, 0, stream>>>(h, W2, t);
    k_aggregate<<<N_NODES / 4, 256, 0, stream>>>(t, offs, cnt, csr, b2, h);
    k_transform<<<512, 256, 0, stream>>>(h, W3, t);
    k_aggregate<<<N_NODES / 4, 256, 0, stream>>>(t, offs, cnt, csr, b3, h);

    k_pool_final<<<G_GRAPHS, 256, 0, stream>>>(h, bat, lw, lb, out);
}